// Round 13
// baseline (110.154 us; speedup 1.0000x reference)
//
#include <hip/hip_runtime.h>

#define MARGIN 0.2f
#define LAMBDA_CONSISTENCY 0.1f
#define COS_EPS 1e-8f

#define B_DIM 8192
#define NBLK  512   // 16 rows/block, 2 blocks/CU
#define NPART NBLK

// ---------------------------------------------------------------------------
// Fused pass — R12 body with ONE change: 2 rows per barrier-window to double
// per-wave outstanding loads (4 -> 8 float4 = 2KB in flight). Iteration kk:
//   issue loads a(k),c(k+1) [own rows] + b(ha_k),e(ha_k+1) [partner rows];
//   stage a->bufA, c->bufC (a,c die); d/s dots from regs (b,e die);
//   shfl-reduce 4 values -> red; barrier A;
//   gather both rows from LDS (v re-read, ht gather); t0 row-stores;
//   barrier B (reuse guard).
// Barriers/row unchanged (1); MLP doubled. Register peak ~60 by ordering
// (a,c die at stage+dot before gather temps come live). If VGPR>64 the
// occupancy halves — that is the experiment's failure signal, revert to R12.
// Column epilogue: plain-store partials (R12, measured win vs atomics).
// ---------------------------------------------------------------------------
__global__ __launch_bounds__(1024) void fused_pass_kernel(
    const float* __restrict__ S, const int* __restrict__ ha,
    const int* __restrict__ ht,
    float* __restrict__ dot_col, float* __restrict__ colsq,
    float* __restrict__ dot_row, float* __restrict__ rowsq,
    float* __restrict__ dpart, float* __restrict__ spart,
    int B, int rows_per_block) {
  extern __shared__ float lds[];     // 2*B staging + 64 reduction slots
  float* bufA = lds;
  float* bufC = lds + B;
  float* red  = lds + 2 * B;         // red[64]: d0,s0,d1,s1 x 16 waves
  const int t = threadIdx.x;

  float dacc[8], sacc[8];
  int hti[8];
#pragma unroll
  for (int c = 0; c < 8; ++c) {
    dacc[c] = 0.f;
    sacc[c] = 0.f;
    hti[c] = ht[t + 1024 * c];
  }

  const int k0 = blockIdx.x * rows_per_block;

  for (int k = k0; k < k0 + rows_per_block; k += 2) {
    const float4* rowk  = (const float4*)(S + (size_t)k * B);
    const float4* rowk1 = (const float4*)(S + (size_t)(k + 1) * B);
    const float4* rowa  = (const float4*)(S + (size_t)ha[k] * B);
    const float4* rowa1 = (const float4*)(S + (size_t)ha[k + 1] * B);

    // 8 independent float4 loads issued before any use (the MLP point)
    float4 a0 = rowk[t],  a1 = rowk[t + 1024];
    float4 c0 = rowk1[t], c1 = rowk1[t + 1024];
    float4 b0 = rowa[t],  b1 = rowa[t + 1024];
    float4 e0 = rowa1[t], e1 = rowa1[t + 1024];

    ((float4*)bufA)[t] = a0;
    ((float4*)bufA)[t + 1024] = a1;
    ((float4*)bufC)[t] = c0;
    ((float4*)bufC)[t + 1024] = c1;

    float d0 = a0.x * b0.x + a0.y * b0.y + a0.z * b0.z + a0.w * b0.w
             + a1.x * b1.x + a1.y * b1.y + a1.z * b1.z + a1.w * b1.w;
    float s0 = a0.x * a0.x + a0.y * a0.y + a0.z * a0.z + a0.w * a0.w
             + a1.x * a1.x + a1.y * a1.y + a1.z * a1.z + a1.w * a1.w;
    float d1 = c0.x * e0.x + c0.y * e0.y + c0.z * e0.z + c0.w * e0.w
             + c1.x * e1.x + c1.y * e1.y + c1.z * e1.z + c1.w * e1.w;
    float s1 = c0.x * c0.x + c0.y * c0.y + c0.z * c0.z + c0.w * c0.w
             + c1.x * c1.x + c1.y * c1.y + c1.z * c1.z + c1.w * c1.w;

#pragma unroll
    for (int o = 32; o > 0; o >>= 1) {
      d0 += __shfl_down(d0, o, 64);
      s0 += __shfl_down(s0, o, 64);
      d1 += __shfl_down(d1, o, 64);
      s1 += __shfl_down(s1, o, 64);
    }
    if ((t & 63) == 0) {
      const int w = t >> 6;
      red[w] = d0; red[16 + w] = s0; red[32 + w] = d1; red[48 + w] = s1;
    }
    __syncthreads();  // barrier A: staging + red visible

#pragma unroll
    for (int c = 0; c < 8; ++c) {
      float v  = bufA[t + 1024 * c];  // conflict-free stride-1
      float g  = bufA[hti[c]];        // random gather (~2-way)
      float v2 = bufC[t + 1024 * c];
      float g2 = bufC[hti[c]];
      dacc[c] += v * g + v2 * g2;
      sacc[c] += v * v + v2 * v2;
    }
    if (t == 0) {
      float dd0 = 0.f, ss0 = 0.f, dd1 = 0.f, ss1 = 0.f;
#pragma unroll
      for (int w = 0; w < 16; ++w) {
        dd0 += red[w]; ss0 += red[16 + w];
        dd1 += red[32 + w]; ss1 += red[48 + w];
      }
      dot_row[k] = dd0;   rowsq[k] = ss0;
      dot_row[k + 1] = dd1; rowsq[k + 1] = ss1;
    }
    __syncthreads();  // barrier B: gathers done, buffers reusable
  }

  if (dpart) {
    float* dp = dpart + (size_t)blockIdx.x * B;
    float* sp = spart + (size_t)blockIdx.x * B;
#pragma unroll
    for (int c = 0; c < 8; ++c) {
      dp[t + 1024 * c] = dacc[c];
      sp[t + 1024 * c] = sacc[c];
    }
  } else {
#pragma unroll
    for (int c = 0; c < 8; ++c) {
      atomicAdd(&dot_col[t + 1024 * c], dacc[c]);
      atomicAdd(&colsq[t + 1024 * c], sacc[c]);
    }
  }
}

// ---------------------------------------------------------------------------
// Reduce partials: 128 blocks x 1024 thr. Block owns 64 columns; thread
// (chunk = t>>6, col = t&63) sums 32 partials; LDS tree over 16 chunks.
// ---------------------------------------------------------------------------
__global__ __launch_bounds__(1024) void reduce_partials(
    const float* __restrict__ dpart, const float* __restrict__ spart,
    float* __restrict__ dot_col, float* __restrict__ colsq) {
  __shared__ float rd[16][64], rs[16][64];
  const int t = threadIdx.x;
  const int c = t & 63, chunk = t >> 6;
  const int col = blockIdx.x * 64 + c;

  float dd = 0.f, ss = 0.f;
  for (int p = chunk * 32; p < chunk * 32 + 32; ++p) {
    dd += dpart[(size_t)p * B_DIM + col];
    ss += spart[(size_t)p * B_DIM + col];
  }
  rd[chunk][c] = dd;
  rs[chunk][c] = ss;
  __syncthreads();
  if (t < 64) {
    float d2 = 0.f, s2 = 0.f;
#pragma unroll
    for (int q = 0; q < 16; ++q) { d2 += rd[q][t]; s2 += rs[q][t]; }
    dot_col[blockIdx.x * 64 + t] = d2;
    colsq[blockIdx.x * 64 + t] = s2;
  }
}

// ---------------------------------------------------------------------------
// Finalize stage 1: 32 blocks x 256 thr, one i per thread.
// ---------------------------------------------------------------------------
__global__ __launch_bounds__(256) void finalize_partials(
    const float* __restrict__ S, const unsigned char* __restrict__ pmask,
    const int* __restrict__ ha, const int* __restrict__ ht,
    const float* __restrict__ dot_col, const float* __restrict__ colsq,
    const float* __restrict__ dot_row, const float* __restrict__ rowsq,
    float* __restrict__ scal) {
  const int t = threadIdx.x;
  const int i = blockIdx.x * 256 + t;

  const int a = ha[i];
  const int x = ht[i];
  const float m = pmask[(size_t)i * B_DIM + i] ? 1.f : 0.f;
  const float pos = S[(size_t)i * B_DIM + i];
  const float an  = S[(size_t)a * B_DIM + i];
  const float tn  = S[(size_t)i * B_DIM + x];

  float trip = fmaxf(MARGIN - pos + tn, 0.f) + fmaxf(MARGIN - pos + an, 0.f);
  const float cosA = dot_row[i] / fmaxf(sqrtf(rowsq[i]) * sqrtf(rowsq[a]), COS_EPS);
  const float cosT = dot_col[i] / fmaxf(sqrtf(colsq[i]) * sqrtf(colsq[x]), COS_EPS);
  float cons = fabsf(cosA - cosT);  // SIGMA_MARGIN = 0

  float cnt = m;
  trip *= m;
  cons *= m;

#pragma unroll
  for (int o = 32; o > 0; o >>= 1) {
    cnt  += __shfl_down(cnt, o, 64);
    trip += __shfl_down(trip, o, 64);
    cons += __shfl_down(cons, o, 64);
  }
  __shared__ float red[12];
  const int wid = t >> 6, lane = t & 63;
  if (lane == 0) { red[wid] = cnt; red[4 + wid] = trip; red[8 + wid] = cons; }
  __syncthreads();
  if (t == 0) {
    atomicAdd(&scal[0], red[0] + red[1] + red[2] + red[3]);
    atomicAdd(&scal[1], red[4] + red[5] + red[6] + red[7]);
    atomicAdd(&scal[2], red[8] + red[9] + red[10] + red[11]);
  }
}

// Finalize stage 2: assemble the 3 outputs.
__global__ void finalize_out(const float* __restrict__ scal,
                             float* __restrict__ out) {
  if (threadIdx.x == 0) {
    const float c = fmaxf(scal[0], 1.f);
    const float triplet = scal[1] / c;
    const float cons = scal[2] / c;
    out[0] = triplet + LAMBDA_CONSISTENCY * cons;
    out[1] = triplet;
    out[2] = cons;
  }
}

extern "C" void kernel_launch(void* const* d_in, const int* in_sizes, int n_in,
                              void* d_out, int out_size, void* d_ws, size_t ws_size,
                              hipStream_t stream) {
  const float* S = (const float*)d_in[0];
  const unsigned char* pmask = (const unsigned char*)d_in[1];  // jnp bool -> 1B
  const int* ha = (const int*)d_in[2];
  const int* ht = (const int*)d_in[3];
  const int B = in_sizes[2];  // 8192

  float* ws = (float*)d_ws;
  float* dot_col = ws;
  float* colsq   = ws + B_DIM;
  float* scal    = ws + 2 * B_DIM;         // [cnt, trip, cons, pad]
  float* dot_row = ws + 2 * B_DIM + 4;
  float* rowsq   = ws + 3 * B_DIM + 4;

  // partials region (33.5 MB) after the base layout
  const size_t part_off = 40960;           // floats
  const size_t need = (part_off + 2ULL * NPART * B_DIM) * sizeof(float);
  const bool use_part = ws_size >= need;
  float* dpart = use_part ? ws + part_off : nullptr;
  float* spart = use_part ? ws + part_off + (size_t)NPART * B_DIM : nullptr;

  if (use_part) {
    hipMemsetAsync(scal, 0, 4 * sizeof(float), stream);
  } else {
    hipMemsetAsync(ws, 0, (size_t)(2 * B_DIM + 4) * sizeof(float), stream);
  }

  fused_pass_kernel<<<NBLK, 1024, (2 * B_DIM + 64) * sizeof(float), stream>>>(
      S, ha, ht, dot_col, colsq, dot_row, rowsq, dpart, spart, B, B / NBLK);

  if (use_part)
    reduce_partials<<<B_DIM / 64, 1024, 0, stream>>>(dpart, spart, dot_col, colsq);

  finalize_partials<<<B_DIM / 256, 256, 0, stream>>>(
      S, pmask, ha, ht, dot_col, colsq, dot_row, rowsq, scal);

  finalize_out<<<1, 64, 0, stream>>>(scal, (float*)d_out);
}

// Round 14
// 106.044 us; speedup vs baseline: 1.0388x; 1.0388x over previous
//
#include <hip/hip_runtime.h>

#define MARGIN 0.2f
#define LAMBDA_CONSISTENCY 0.1f
#define COS_EPS 1e-8f

#define B_DIM 8192
#define NBLK  512   // 16 rows/block, 2 blocks/CU
#define NPART NBLK

// ---------------------------------------------------------------------------
// Fused pass — R12 configuration VERBATIM (measured 106.2µs total, the best).
// R13's 2-row batching regressed (110.2); R3/R5/R6/R7 pipelining all lost.
// Structure: per row k, load row k + row ha[k] -> regs; stage row k into
// buf[k&1] (double buffer => ONE barrier/row); row dot/norm shfl-reduced
// before the barrier; after the barrier, own-cols re-read from LDS + ht
// gather; t0 stores row outputs. Column partials plain-stored per block at
// kernel end (no atomics), reduced by reduce_partials.
// ---------------------------------------------------------------------------
__global__ __launch_bounds__(1024) void fused_pass_kernel(
    const float* __restrict__ S, const int* __restrict__ ha,
    const int* __restrict__ ht,
    float* __restrict__ dot_col, float* __restrict__ colsq,
    float* __restrict__ dot_row, float* __restrict__ rowsq,
    float* __restrict__ dpart, float* __restrict__ spart,
    int B, int rows_per_block) {
  extern __shared__ float lds[];     // 2*B staging + 2*32 reduction slots
  float* red = lds + 2 * B;          // red[2][32]
  const int t = threadIdx.x;

  float dacc[8], sacc[8];
  int hti[8];
#pragma unroll
  for (int c = 0; c < 8; ++c) {
    dacc[c] = 0.f;
    sacc[c] = 0.f;
    hti[c] = ht[t + 1024 * c];
  }

  const int k0 = blockIdx.x * rows_per_block;

  for (int k = k0; k < k0 + rows_per_block; ++k) {
    const int p = k & 1;
    float* buf = lds + (p ? B : 0);
    float4* buf4 = (float4*)buf;
    float* redk = red + (p << 5);

    const float4* rowk = (const float4*)(S + (size_t)k * B);
    const float4* rowa = (const float4*)(S + (size_t)ha[k] * B);
    float4 a0 = rowk[t], a1 = rowk[t + 1024];
    float4 b0 = rowa[t], b1 = rowa[t + 1024];
    buf4[t] = a0;
    buf4[t + 1024] = a1;

    float d = a0.x * b0.x + a0.y * b0.y + a0.z * b0.z + a0.w * b0.w
            + a1.x * b1.x + a1.y * b1.y + a1.z * b1.z + a1.w * b1.w;
    float s = a0.x * a0.x + a0.y * a0.y + a0.z * a0.z + a0.w * a0.w
            + a1.x * a1.x + a1.y * a1.y + a1.z * a1.z + a1.w * a1.w;
#pragma unroll
    for (int o = 32; o > 0; o >>= 1) {
      d += __shfl_down(d, o, 64);
      s += __shfl_down(s, o, 64);
    }
    if ((t & 63) == 0) { redk[t >> 6] = d; redk[16 + (t >> 6)] = s; }
    __syncthreads();  // staging + red visible (the ONLY barrier per row)

#pragma unroll
    for (int c = 0; c < 8; ++c) {
      float v = buf[t + 1024 * c];  // stride-1 across lanes: conflict-free
      float g = buf[hti[c]];        // random gather within row (~2-way)
      dacc[c] += v * g;
      sacc[c] += v * v;
    }
    if (t == 0) {
      float dd = 0.f, ss = 0.f;
#pragma unroll
      for (int w = 0; w < 16; ++w) { dd += redk[w]; ss += redk[16 + w]; }
      dot_row[k] = dd;
      rowsq[k] = ss;
    }
  }

  if (dpart) {
    // plain-store partials: coalesced (consecutive t -> consecutive cols)
    float* dp = dpart + (size_t)blockIdx.x * B;
    float* sp = spart + (size_t)blockIdx.x * B;
#pragma unroll
    for (int c = 0; c < 8; ++c) {
      dp[t + 1024 * c] = dacc[c];
      sp[t + 1024 * c] = sacc[c];
    }
  } else {
#pragma unroll
    for (int c = 0; c < 8; ++c) {
      atomicAdd(&dot_col[t + 1024 * c], dacc[c]);
      atomicAdd(&colsq[t + 1024 * c], sacc[c]);
    }
  }
}

// ---------------------------------------------------------------------------
// Reduce partials: 128 blocks x 1024 thr. Block owns 64 columns; thread
// (chunk = t>>6, col = t&63) sums 32 partials; LDS tree over 16 chunks.
// ---------------------------------------------------------------------------
__global__ __launch_bounds__(1024) void reduce_partials(
    const float* __restrict__ dpart, const float* __restrict__ spart,
    float* __restrict__ dot_col, float* __restrict__ colsq) {
  __shared__ float rd[16][64], rs[16][64];
  const int t = threadIdx.x;
  const int c = t & 63, chunk = t >> 6;
  const int col = blockIdx.x * 64 + c;

  float dd = 0.f, ss = 0.f;
  for (int p = chunk * 32; p < chunk * 32 + 32; ++p) {
    dd += dpart[(size_t)p * B_DIM + col];
    ss += spart[(size_t)p * B_DIM + col];
  }
  rd[chunk][c] = dd;
  rs[chunk][c] = ss;
  __syncthreads();
  if (t < 64) {
    float d2 = 0.f, s2 = 0.f;
#pragma unroll
    for (int q = 0; q < 16; ++q) { d2 += rd[q][t]; s2 += rs[q][t]; }
    dot_col[blockIdx.x * 64 + t] = d2;
    colsq[blockIdx.x * 64 + t] = s2;
  }
}

// ---------------------------------------------------------------------------
// Finalize stage 1: 32 blocks x 256 thr, one i per thread.
// ---------------------------------------------------------------------------
__global__ __launch_bounds__(256) void finalize_partials(
    const float* __restrict__ S, const unsigned char* __restrict__ pmask,
    const int* __restrict__ ha, const int* __restrict__ ht,
    const float* __restrict__ dot_col, const float* __restrict__ colsq,
    const float* __restrict__ dot_row, const float* __restrict__ rowsq,
    float* __restrict__ scal) {
  const int t = threadIdx.x;
  const int i = blockIdx.x * 256 + t;

  const int a = ha[i];
  const int x = ht[i];
  const float m = pmask[(size_t)i * B_DIM + i] ? 1.f : 0.f;
  const float pos = S[(size_t)i * B_DIM + i];
  const float an  = S[(size_t)a * B_DIM + i];
  const float tn  = S[(size_t)i * B_DIM + x];

  float trip = fmaxf(MARGIN - pos + tn, 0.f) + fmaxf(MARGIN - pos + an, 0.f);
  const float cosA = dot_row[i] / fmaxf(sqrtf(rowsq[i]) * sqrtf(rowsq[a]), COS_EPS);
  const float cosT = dot_col[i] / fmaxf(sqrtf(colsq[i]) * sqrtf(colsq[x]), COS_EPS);
  float cons = fabsf(cosA - cosT);  // SIGMA_MARGIN = 0

  float cnt = m;
  trip *= m;
  cons *= m;

#pragma unroll
  for (int o = 32; o > 0; o >>= 1) {
    cnt  += __shfl_down(cnt, o, 64);
    trip += __shfl_down(trip, o, 64);
    cons += __shfl_down(cons, o, 64);
  }
  __shared__ float red[12];
  const int wid = t >> 6, lane = t & 63;
  if (lane == 0) { red[wid] = cnt; red[4 + wid] = trip; red[8 + wid] = cons; }
  __syncthreads();
  if (t == 0) {
    atomicAdd(&scal[0], red[0] + red[1] + red[2] + red[3]);
    atomicAdd(&scal[1], red[4] + red[5] + red[6] + red[7]);
    atomicAdd(&scal[2], red[8] + red[9] + red[10] + red[11]);
  }
}

// Finalize stage 2: assemble the 3 outputs.
__global__ void finalize_out(const float* __restrict__ scal,
                             float* __restrict__ out) {
  if (threadIdx.x == 0) {
    const float c = fmaxf(scal[0], 1.f);
    const float triplet = scal[1] / c;
    const float cons = scal[2] / c;
    out[0] = triplet + LAMBDA_CONSISTENCY * cons;
    out[1] = triplet;
    out[2] = cons;
  }
}

extern "C" void kernel_launch(void* const* d_in, const int* in_sizes, int n_in,
                              void* d_out, int out_size, void* d_ws, size_t ws_size,
                              hipStream_t stream) {
  const float* S = (const float*)d_in[0];
  const unsigned char* pmask = (const unsigned char*)d_in[1];  // jnp bool -> 1B
  const int* ha = (const int*)d_in[2];
  const int* ht = (const int*)d_in[3];
  const int B = in_sizes[2];  // 8192

  float* ws = (float*)d_ws;
  float* dot_col = ws;
  float* colsq   = ws + B_DIM;
  float* scal    = ws + 2 * B_DIM;         // [cnt, trip, cons, pad]
  float* dot_row = ws + 2 * B_DIM + 4;
  float* rowsq   = ws + 3 * B_DIM + 4;

  // partials region (33.5 MB) after the base layout
  const size_t part_off = 40960;           // floats
  const size_t need = (part_off + 2ULL * NPART * B_DIM) * sizeof(float);
  const bool use_part = ws_size >= need;
  float* dpart = use_part ? ws + part_off : nullptr;
  float* spart = use_part ? ws + part_off + (size_t)NPART * B_DIM : nullptr;

  if (use_part) {
    hipMemsetAsync(scal, 0, 4 * sizeof(float), stream);
  } else {
    hipMemsetAsync(ws, 0, (size_t)(2 * B_DIM + 4) * sizeof(float), stream);
  }

  fused_pass_kernel<<<NBLK, 1024, (2 * B_DIM + 64) * sizeof(float), stream>>>(
      S, ha, ht, dot_col, colsq, dot_row, rowsq, dpart, spart, B, B / NBLK);

  if (use_part)
    reduce_partials<<<B_DIM / 64, 1024, 0, stream>>>(dpart, spart, dot_col, colsq);

  finalize_partials<<<B_DIM / 256, 256, 0, stream>>>(
      S, pmask, ha, ht, dot_col, colsq, dot_row, rowsq, scal);

  finalize_out<<<1, 64, 0, stream>>>(scal, (float*)d_out);
}